// Round 8
// baseline (576.194 us; speedup 1.0000x reference)
//
#include <hip/hip_runtime.h>

// ---------------- problem constants ----------------
#define CDIM 1152
#define NDIS 30
#define NVOX (64*64*64)        // 262144 voxels
#define NT   256               // voxels per block
#define NBLK3 (NVOX/NT)        // 1024 blocks
#define KSTEPS (CDIM/32)       // 36 K-steps of 32 channels
#define LROW 257               // padded LDS row stride (floats): bank-conflict-free B-reads

// ---------------- workspace layout (float offsets) ----------------
#define AF_FLOATS 73728
#define PM_OFF AF_FLOATS                    // [30][1024] per-block max of s
#define PD_OFF (PM_OFF + NDIS*NBLK3)        // [30][1024] per-block sum e
#define PN_OFF (PD_OFF + NDIS*NBLK3)        // [30][1024] per-block sum e*h
#define CNT_OFF (PN_OFF + NDIS*NBLK3)       // 1 uint: blocks-done counter (k_prep zeroes)

typedef float f32x4 __attribute__((ext_vector_type(4)));
typedef short bf16x8 __attribute__((ext_vector_type(8)));

__device__ inline short f2bf(float f) {
    unsigned u = __float_as_uint(f);
    unsigned r = (u + 0x7FFFu + ((u >> 16) & 1u)) >> 16;
    return (short)r;
}
__device__ inline float bf2f(short h) {
    return __uint_as_float(((unsigned)(unsigned short)h) << 16);
}
__device__ inline float inv_tau(float t) {
    float sig = 1.f / (1.f + expf(-t));
    return 1.f / (0.2f + 1.8f * sig);
}

// K0: precompute per-lane A-fragments (weights, bf16 hi/lo split) + zero the
// done-counter (ws is poisoned once, never re-poisoned -> kernel owns reset).
// A-row m = lane&15 (0..29 score_w, 30..59 head_w, 60..63 zero); k = 8*(lane>>4)+e.
__global__ void k_prep(const float* __restrict__ score_w,
                       const float* __restrict__ head_w,
                       short* __restrict__ afrag,
                       unsigned* __restrict__ counter) {
    if (blockIdx.x == 0 && threadIdx.x == 0) *counter = 0u;
    int idx = blockIdx.x * 256 + threadIdx.x;      // 147456 total
    int e  = idx & 7;
    int l  = (idx >> 3) & 63;
    int p  = (idx >> 9) & 1;
    int mt = (idx >> 10) & 3;
    int t  = idx >> 12;
    if (t >= KSTEPS) return;
    int m = mt * 16 + (l & 15);
    int k = t * 32 + 8 * (l >> 4) + e;
    float w = 0.f;
    if (m < NDIS)          w = score_w[m * CDIM + k];
    else if (m < 2 * NDIS) w = head_w[(m - NDIS) * CDIM + k];
    short hi = f2bf(w);
    afrag[idx] = p ? f2bf(w - bf2f(hi)) : hi;
}

// K1 (hot): 512 threads / 8 waves, NT=256. Each global_load_lds covers one
// FULL 1KB-contiguous aligned row-slice (64 lanes x 16B). Proven r7 ordering:
// __syncthreads drain, then A(t) loads (L2), sched_barrier, stage(t+1) (HBM,
// stays in flight across compute), compute. Epilogue computes per-block
// softmax partials; the LAST block (threadfence+atomic counter) merges all
// 1024 partials with max-rescaling and writes out[30] — replaces k_final.
__global__ __launch_bounds__(512, 4) void k_mfma(const float* __restrict__ activ,
                                                 const short* __restrict__ afrag,
                                                 const float* __restrict__ temp_logit,
                                                 const float* __restrict__ head_b,
                                                 float* __restrict__ pm,
                                                 float* __restrict__ pd,
                                                 float* __restrict__ pn,
                                                 unsigned* __restrict__ counter,
                                                 float* __restrict__ out) {
    __shared__ float lds[2][32][LROW];        // 64.2 KB staging (padded rows)
    __shared__ float redm[32][16], rede[32][16], redh[32][16];
    __shared__ int is_last;

    const int tid  = threadIdx.x;
    const int lane = tid & 63;
    const int w    = tid >> 6;                // wave 0..7
    const int a    = lane >> 4;               // k-group 0..3
    const int i16  = lane & 15;
    const int nb   = blockIdx.x * NT;

    const bf16x8* afp = (const bf16x8*)afrag;

    f32x4 acc[4][2];
#pragma unroll
    for (int mt = 0; mt < 4; mt++)
#pragma unroll
        for (int nt = 0; nt < 2; nt++) acc[mt][nt] = (f32x4)0.f;

    // stage K-step t's [32][256] f32 tile into buffer b: wave w stages rows
    // 4w..4w+3, one 1KB-contiguous global_load_lds per row (lane offset 16B).
    auto stage = [&](int t, int b) {
#pragma unroll
        for (int q = 0; q < 4; q++) {
            const int row = 4 * w + q;                           // wave-uniform
            const float* g = activ + (size_t)(t * 32 + row) * NVOX + nb + lane * 4;
            __builtin_amdgcn_global_load_lds(
                (const __attribute__((address_space(1))) unsigned int*)g,
                (__attribute__((address_space(3))) unsigned int*)&lds[b][row][0],
                16, 0, 0);
        }
    };

    stage(0, 0);
#pragma unroll 1
    for (int t = 0; t < KSTEPS; t++) {
        const int b = t & 1;
        __syncthreads();                      // vmcnt(0)+barrier: buf b fully staged

        // A fragments first (L2-resident): their wait retires before the
        // stage(t+1) HBM loads issued below (in-order vmcnt).
        bf16x8 ah[4], al[4];
#pragma unroll
        for (int mt = 0; mt < 4; mt++) {
            ah[mt] = afp[(size_t)(t * 8 + mt * 2 + 0) * 64 + lane];
            al[mt] = afp[(size_t)(t * 8 + mt * 2 + 1) * 64 + lane];
        }
        __builtin_amdgcn_sched_barrier(0);    // pin: A-loads issue before stage(t+1)

        if (t + 1 < KSTEPS) stage(t + 1, 1 - b);   // in flight across compute

        // B fragments: padded stride makes these reads bank-conflict-free
        bf16x8 bh[2], bl[2];
#pragma unroll
        for (int nt = 0; nt < 2; nt++) {
            const int col = w * 32 + nt * 16 + i16;
#pragma unroll
            for (int e = 0; e < 8; e++) {
                float f = lds[b][8 * a + e][col];
                short hs = f2bf(f);                               // RTNE hi
                bh[nt][e] = hs;
                float lf = f - bf2f(hs);
                bl[nt][e] = (short)(__float_as_uint(lf) >> 16);   // trunc lo
            }
        }

        // 24 MFMA: (hi*hi + hi*lo + lo*hi)
#pragma unroll
        for (int mt = 0; mt < 4; mt++)
#pragma unroll
            for (int nt = 0; nt < 2; nt++) {
                acc[mt][nt] = __builtin_amdgcn_mfma_f32_16x16x32_bf16(ah[mt], bh[nt], acc[mt][nt], 0, 0, 0);
                acc[mt][nt] = __builtin_amdgcn_mfma_f32_16x16x32_bf16(ah[mt], bl[nt], acc[mt][nt], 0, 0, 0);
                acc[mt][nt] = __builtin_amdgcn_mfma_f32_16x16x32_bf16(al[mt], bh[nt], acc[mt][nt], 0, 0, 0);
            }
    }

    // ---- epilogue: dump D[64][256] to LDS (stride LROW), softmax partials ----
    __syncthreads();                          // everyone done reading staging LDS
    float* epf = &lds[0][0][0];               // 64 rows x LROW overlay (fits exactly)
#pragma unroll
    for (int mt = 0; mt < 4; mt++)
#pragma unroll
        for (int nt = 0; nt < 2; nt++)
#pragma unroll
            for (int r = 0; r < 4; r++) {
                int m = mt * 16 + a * 4 + r;  // verified C/D map: row=(lane>>4)*4+reg
                int n = w * 32 + nt * 16 + i16;
                epf[m * LROW + n] = acc[mt][nt][r];
            }
    __syncthreads();

    const int d   = tid >> 4;                 // 0..31 (30 used)
    const int j16 = tid & 15;                 // 16 threads per disease
    if (d < NDIS) {
        float mx = -3.4e38f;
        for (int i = 0; i < 16; i++) mx = fmaxf(mx, epf[d * LROW + j16 * 16 + i]);
        redm[d][j16] = mx;
    }
    __syncthreads();
    if (d < NDIS) {
        float mb = redm[d][0];
        for (int j = 1; j < 16; j++) mb = fmaxf(mb, redm[d][j]);
        float it = inv_tau(temp_logit[d]);
        float se = 0.f, sh = 0.f;
        for (int i = 0; i < 16; i++) {
            float e = expf((epf[d * LROW + j16 * 16 + i] - mb) * it);
            se += e;
            sh += e * epf[(d + NDIS) * LROW + j16 * 16 + i];
        }
        rede[d][j16] = se;
        redh[d][j16] = sh;
    }
    __syncthreads();
    if (tid < NDIS) {
        float mb = redm[tid][0];
        for (int j = 1; j < 16; j++) mb = fmaxf(mb, redm[tid][j]);
        float se = 0.f, sh = 0.f;
        for (int j = 0; j < 16; j++) { se += rede[tid][j]; sh += redh[tid][j]; }
        pm[tid * NBLK3 + blockIdx.x] = mb;
        pd[tid * NBLK3 + blockIdx.x] = se;
        pn[tid * NBLK3 + blockIdx.x] = sh;
    }

    // ---- last-block final reduction (replaces k_final; deterministic) ----
    __threadfence();                          // release: partials visible device-wide
    __syncthreads();                          // all threads' fences done
    if (tid == 0) {
        unsigned v = atomicAdd(counter, 1u);  // device-scope (G12)
        is_last = (v == (unsigned)(NBLK3 - 1));
    }
    __syncthreads();
    if (!is_last) return;
    __threadfence();                          // acquire: see all blocks' partials

    // wave w handles diseases w, w+8, w+16, w+24; lane-strided over 1024
    // partials in fixed order + fixed shuffle tree -> bit-deterministic.
#pragma unroll 1
    for (int dd = w; dd < NDIS + 2; dd += 8) {
        if (dd >= NDIS) break;
        const float* bm = pm + dd * NBLK3;
        const float* bd = pd + dd * NBLK3;
        const float* bn = pn + dd * NBLK3;
        float mx = -3.4e38f;
#pragma unroll 4
        for (int i = lane; i < NBLK3; i += 64) mx = fmaxf(mx, bm[i]);
#pragma unroll
        for (int off = 32; off > 0; off >>= 1) mx = fmaxf(mx, __shfl_xor(mx, off));
        const float M = mx;
        const float it = inv_tau(temp_logit[dd]);
        float den = 0.f, num = 0.f;
#pragma unroll 4
        for (int i = lane; i < NBLK3; i += 64) {
            float sc = expf((bm[i] - M) * it);
            den += bd[i] * sc;
            num += bn[i] * sc;
        }
#pragma unroll
        for (int off = 32; off > 0; off >>= 1) {
            den += __shfl_xor(den, off);
            num += __shfl_xor(num, off);
        }
        if (lane == 0) {
            float o = num / fmaxf(den, 1e-12f) + head_b[dd];
            if (o != o) o = 0.f;              // NaN guard (mirrors reference)
            out[dd] = o;
        }
    }
}

extern "C" void kernel_launch(void* const* d_in, const int* in_sizes, int n_in,
                              void* d_out, int out_size, void* d_ws, size_t ws_size,
                              hipStream_t stream) {
    const float* activ      = (const float*)d_in[0];
    const float* score_w    = (const float*)d_in[1];
    // d_in[2] = score_b — cancels exactly in the stable softmax, unused
    const float* head_w     = (const float*)d_in[3];
    const float* head_b     = (const float*)d_in[4];
    const float* temp_logit = (const float*)d_in[5];
    float* ws  = (float*)d_ws;
    float* out = (float*)d_out;

    short*    afrag   = (short*)ws;
    unsigned* counter = (unsigned*)(ws + CNT_OFF);

    k_prep <<<576,   256, 0, stream>>>(score_w, head_w, afrag, counter);
    k_mfma <<<NBLK3, 512, 0, stream>>>(activ, afrag, temp_logit, head_b,
                                       ws + PM_OFF, ws + PD_OFF, ws + PN_OFF,
                                       counter, out);
}

// Round 9
// 228.776 us; speedup vs baseline: 2.5186x; 2.5186x over previous
//
#include <hip/hip_runtime.h>

// ---------------- problem constants ----------------
#define CDIM 1152
#define NDIS 30
#define NVOX (64*64*64)        // 262144 voxels
#define NT   256               // voxels per block
#define NBLK3 (NVOX/NT)        // 1024 blocks
#define KSTEPS (CDIM/32)       // 36 K-steps of 32 channels
#define LROW 257               // padded LDS row stride (floats): bank-conflict-free B-reads

// ---------------- workspace layout (float offsets) ----------------
#define AF_FLOATS 73728
#define PM_OFF AF_FLOATS                    // [30][1024] per-block max of s
#define PD_OFF (PM_OFF + NDIS*NBLK3)        // [30][1024] per-block sum e
#define PN_OFF (PD_OFF + NDIS*NBLK3)        // [30][1024] per-block sum e*h

typedef float f32x4 __attribute__((ext_vector_type(4)));
typedef short bf16x8 __attribute__((ext_vector_type(8)));

__device__ inline short f2bf(float f) {
    unsigned u = __float_as_uint(f);
    unsigned r = (u + 0x7FFFu + ((u >> 16) & 1u)) >> 16;
    return (short)r;
}
__device__ inline float bf2f(short h) {
    return __uint_as_float(((unsigned)(unsigned short)h) << 16);
}
__device__ inline float inv_tau(float t) {
    float sig = 1.f / (1.f + expf(-t));
    return 1.f / (0.2f + 1.8f * sig);
}

// K0: precompute per-lane A-fragments (weights, bf16 hi/lo split).
// A-row m = lane&15 (0..29 score_w, 30..59 head_w, 60..63 zero); k = 8*(lane>>4)+e.
__global__ void k_prep(const float* __restrict__ score_w,
                       const float* __restrict__ head_w,
                       short* __restrict__ afrag) {
    int idx = blockIdx.x * 256 + threadIdx.x;      // 147456 total
    int e  = idx & 7;
    int l  = (idx >> 3) & 63;
    int p  = (idx >> 9) & 1;
    int mt = (idx >> 10) & 3;
    int t  = idx >> 12;
    if (t >= KSTEPS) return;
    int m = mt * 16 + (l & 15);
    int k = t * 32 + 8 * (l >> 4) + e;
    float w = 0.f;
    if (m < NDIS)          w = score_w[m * CDIM + k];
    else if (m < 2 * NDIS) w = head_w[(m - NDIS) * CDIM + k];
    short hi = f2bf(w);
    afrag[idx] = p ? f2bf(w - bf2f(hi)) : hi;
}

// K1 (hot): 512 threads / 8 waves, NT=256. Each global_load_lds covers one
// FULL 1KB-contiguous aligned row-slice (64 lanes x 16B). r7-proven ordering:
// __syncthreads drain, then A(t) loads (L2), sched_barrier, stage(t+1) (HBM,
// stays in flight across compute), compute.
// ROUND-9 CHANGE: staging loads carry CPol NT (aux=2, non-temporal) — the
// activ stream is read-once; NT stops it thrashing L2 so the 8x-reused
// A-fragments stay L2-resident. Hint-only: zero correctness risk.
__global__ __launch_bounds__(512, 4) void k_mfma(const float* __restrict__ activ,
                                                 const short* __restrict__ afrag,
                                                 const float* __restrict__ temp_logit,
                                                 float* __restrict__ pm,
                                                 float* __restrict__ pd,
                                                 float* __restrict__ pn) {
    __shared__ float lds[2][32][LROW];        // 64.2 KB staging (padded rows)
    __shared__ float redm[32][16], rede[32][16], redh[32][16];

    const int tid  = threadIdx.x;
    const int lane = tid & 63;
    const int w    = tid >> 6;                // wave 0..7
    const int a    = lane >> 4;               // k-group 0..3
    const int i16  = lane & 15;
    const int nb   = blockIdx.x * NT;

    const bf16x8* afp = (const bf16x8*)afrag;

    f32x4 acc[4][2];
#pragma unroll
    for (int mt = 0; mt < 4; mt++)
#pragma unroll
        for (int nt = 0; nt < 2; nt++) acc[mt][nt] = (f32x4)0.f;

    // stage K-step t's [32][256] f32 tile into buffer b: wave w stages rows
    // 4w..4w+3, one 1KB-contiguous global_load_lds per row (lane offset 16B).
    auto stage = [&](int t, int b) {
#pragma unroll
        for (int q = 0; q < 4; q++) {
            const int row = 4 * w + q;                           // wave-uniform
            const float* g = activ + (size_t)(t * 32 + row) * NVOX + nb + lane * 4;
            __builtin_amdgcn_global_load_lds(
                (const __attribute__((address_space(1))) unsigned int*)g,
                (__attribute__((address_space(3))) unsigned int*)&lds[b][row][0],
                16, 0, /*aux=CPol.NT*/ 2);
        }
    };

    stage(0, 0);
#pragma unroll 1
    for (int t = 0; t < KSTEPS; t++) {
        const int b = t & 1;
        __syncthreads();                      // vmcnt(0)+barrier: buf b fully staged

        // A fragments first (L2-resident): their wait retires before the
        // stage(t+1) HBM loads issued below (in-order vmcnt).
        bf16x8 ah[4], al[4];
#pragma unroll
        for (int mt = 0; mt < 4; mt++) {
            ah[mt] = afp[(size_t)(t * 8 + mt * 2 + 0) * 64 + lane];
            al[mt] = afp[(size_t)(t * 8 + mt * 2 + 1) * 64 + lane];
        }
        __builtin_amdgcn_sched_barrier(0);    // pin: A-loads issue before stage(t+1)

        if (t + 1 < KSTEPS) stage(t + 1, 1 - b);   // in flight across compute

        // B fragments: padded stride makes these reads bank-conflict-free
        bf16x8 bh[2], bl[2];
#pragma unroll
        for (int nt = 0; nt < 2; nt++) {
            const int col = w * 32 + nt * 16 + i16;
#pragma unroll
            for (int e = 0; e < 8; e++) {
                float f = lds[b][8 * a + e][col];
                short hs = f2bf(f);                               // RTNE hi
                bh[nt][e] = hs;
                float lf = f - bf2f(hs);
                bl[nt][e] = (short)(__float_as_uint(lf) >> 16);   // trunc lo
            }
        }

        // 24 MFMA: (hi*hi + hi*lo + lo*hi)
#pragma unroll
        for (int mt = 0; mt < 4; mt++)
#pragma unroll
            for (int nt = 0; nt < 2; nt++) {
                acc[mt][nt] = __builtin_amdgcn_mfma_f32_16x16x32_bf16(ah[mt], bh[nt], acc[mt][nt], 0, 0, 0);
                acc[mt][nt] = __builtin_amdgcn_mfma_f32_16x16x32_bf16(ah[mt], bl[nt], acc[mt][nt], 0, 0, 0);
                acc[mt][nt] = __builtin_amdgcn_mfma_f32_16x16x32_bf16(al[mt], bh[nt], acc[mt][nt], 0, 0, 0);
            }
    }

    // ---- epilogue: dump D[64][256] to LDS (stride LROW), softmax partials ----
    __syncthreads();                          // everyone done reading staging LDS
    float* epf = &lds[0][0][0];               // 64 rows x LROW overlay (fits exactly)
#pragma unroll
    for (int mt = 0; mt < 4; mt++)
#pragma unroll
        for (int nt = 0; nt < 2; nt++)
#pragma unroll
            for (int r = 0; r < 4; r++) {
                int m = mt * 16 + a * 4 + r;  // verified C/D map: row=(lane>>4)*4+reg
                int n = w * 32 + nt * 16 + i16;
                epf[m * LROW + n] = acc[mt][nt][r];
            }
    __syncthreads();

    const int d   = tid >> 4;                 // 0..31 (30 used)
    const int j16 = tid & 15;                 // 16 threads per disease
    if (d < NDIS) {
        float mx = -3.4e38f;
        for (int i = 0; i < 16; i++) mx = fmaxf(mx, epf[d * LROW + j16 * 16 + i]);
        redm[d][j16] = mx;
    }
    __syncthreads();
    if (d < NDIS) {
        float mb = redm[d][0];
        for (int j = 1; j < 16; j++) mb = fmaxf(mb, redm[d][j]);
        float it = inv_tau(temp_logit[d]);
        float se = 0.f, sh = 0.f;
        for (int i = 0; i < 16; i++) {
            float e = expf((epf[d * LROW + j16 * 16 + i] - mb) * it);
            se += e;
            sh += e * epf[(d + NDIS) * LROW + j16 * 16 + i];
        }
        rede[d][j16] = se;
        redh[d][j16] = sh;
    }
    __syncthreads();
    if (tid < NDIS) {
        float mb = redm[tid][0];
        for (int j = 1; j < 16; j++) mb = fmaxf(mb, redm[tid][j]);
        float se = 0.f, sh = 0.f;
        for (int j = 0; j < 16; j++) { se += rede[tid][j]; sh += redh[tid][j]; }
        pm[tid * NBLK3 + blockIdx.x] = mb;
        pd[tid * NBLK3 + blockIdx.x] = se;
        pn[tid * NBLK3 + blockIdx.x] = sh;
    }
}

// K2: merge 1024 per-block partials per disease with max-rescaling.
__global__ __launch_bounds__(256) void k_final(const float* __restrict__ pm,
                                               const float* __restrict__ pd,
                                               const float* __restrict__ pn,
                                               const float* __restrict__ temp_logit,
                                               const float* __restrict__ head_b,
                                               float* __restrict__ out) {
    const int d = blockIdx.x, tid = threadIdx.x;
    const int lane = tid & 63, wid = tid >> 6;
    __shared__ float sm[4], sd[4], sn[4];
    const float* bm = pm + d * NBLK3;
    const float* bd = pd + d * NBLK3;
    const float* bn = pn + d * NBLK3;

    float m[4], e[4], h[4];
#pragma unroll
    for (int i = 0; i < 4; i++) {
        int ix = tid + i * 256;
        m[i] = bm[ix]; e[i] = bd[ix]; h[i] = bn[ix];
    }
    float mx = m[0];
#pragma unroll
    for (int i = 1; i < 4; i++) mx = fmaxf(mx, m[i]);
#pragma unroll
    for (int off = 32; off > 0; off >>= 1) mx = fmaxf(mx, __shfl_xor(mx, off));
    if (lane == 0) sm[wid] = mx;
    __syncthreads();
    float M = fmaxf(fmaxf(sm[0], sm[1]), fmaxf(sm[2], sm[3]));

    float it = inv_tau(temp_logit[d]);
    float den = 0.f, num = 0.f;
#pragma unroll
    for (int i = 0; i < 4; i++) {
        float sc = expf((m[i] - M) * it);
        den += e[i] * sc;
        num += h[i] * sc;
    }
#pragma unroll
    for (int off = 32; off > 0; off >>= 1) {
        den += __shfl_xor(den, off);
        num += __shfl_xor(num, off);
    }
    if (lane == 0) { sd[wid] = den; sn[wid] = num; }
    __syncthreads();
    if (tid == 0) {
        float D = (sd[0] + sd[1]) + (sd[2] + sd[3]);
        float N = (sn[0] + sn[1]) + (sn[2] + sn[3]);
        float o = N / fmaxf(D, 1e-12f) + head_b[d];
        if (o != o) o = 0.f;
        out[d] = o;
    }
}

extern "C" void kernel_launch(void* const* d_in, const int* in_sizes, int n_in,
                              void* d_out, int out_size, void* d_ws, size_t ws_size,
                              hipStream_t stream) {
    const float* activ      = (const float*)d_in[0];
    const float* score_w    = (const float*)d_in[1];
    // d_in[2] = score_b — cancels exactly in the stable softmax, unused
    const float* head_w     = (const float*)d_in[3];
    const float* head_b     = (const float*)d_in[4];
    const float* temp_logit = (const float*)d_in[5];
    float* ws  = (float*)d_ws;
    float* out = (float*)d_out;

    short* afrag = (short*)ws;
    k_prep <<<576,   256, 0, stream>>>(score_w, head_w, afrag);
    k_mfma <<<NBLK3, 512, 0, stream>>>(activ, afrag, temp_logit,
                                       ws + PM_OFF, ws + PD_OFF, ws + PN_OFF);
    k_final<<<NDIS,  256, 0, stream>>>(ws + PM_OFF, ws + PD_OFF, ws + PN_OFF,
                                       temp_logit, head_b, out);
}